// Round 2
// baseline (1079.754 us; speedup 1.0000x reference)
//
#include <hip/hip_runtime.h>
#include <hip/hip_bf16.h>
#include <math.h>

#define N_NODES 50000
#define N_EDGES 800000
#define ET_EDGES (N_EDGES + N_NODES)   // with self-loops
#define CH 64
#define NEG_SLOPE 0.2f

typedef __hip_bfloat16 bf16;

__device__ inline float bfbits(unsigned short u) {
    return __uint_as_float(((unsigned)u) << 16);
}

// monotone float <-> uint mapping for atomicMax on floats
__device__ inline unsigned fmap(float f) {
    unsigned b = __float_as_uint(f);
    return (b & 0x80000000u) ? ~b : (b | 0x80000000u);
}
__device__ inline float funmap(unsigned u) {
    return __uint_as_float((u & 0x80000000u) ? (u ^ 0x80000000u) : ~u);
}

// ---------------- dtype detection ----------------
// Reads W1's first 128 halves as bf16. True-bf16 weights are ~N(0,0.09) so
// every |v| <= 64. True-fp32 data makes the low halves random-exponent
// garbage: P(all 64 lanes pass) ~ 6e-19. flag=1 -> bf16, flag=0 -> fp32.
__global__ void detect_dtype(const unsigned short* __restrict__ w1raw,
                             unsigned* __restrict__ flag)
{
    int t = threadIdx.x;
    float v0 = bfbits(w1raw[2 * t]);
    float v1 = bfbits(w1raw[2 * t + 1]);
    bool bad = !(fabsf(v0) <= 64.f && fabsf(v1) <= 64.f);  // NaN -> bad
    unsigned long long b = __ballot(bad);
    if (t == 0) *flag = (b == 0ull) ? 1u : 0u;
}

// ---------------- param conversion (12 small tensors -> fp32) ----------------
struct CvtArgs {
    const void* src[12];
    float*      dst[12];
    int         n[12];
};

__global__ __launch_bounds__(256)
void convert_params(CvtArgs a, const unsigned* __restrict__ flag)
{
    bool isbf = (*flag != 0u);
    int which = blockIdx.y;
    int n = a.n[which];
    const void* s = a.src[which];
    float* d = a.dst[which];
    for (int i = blockIdx.x * 256 + threadIdx.x; i < n; i += gridDim.x * 256) {
        float v = isbf ? bfbits(((const unsigned short*)s)[i])
                       : ((const float*)s)[i];
        d[i] = v;
    }
}

// ---------------- GEMM + alpha epilogue ----------------
// block = (64,4): tx = output column, ty = row-in-block; one wave per row.
template<int CIN, bool DYN>
__global__ __launch_bounds__(256)
void gemm_alpha(const void* __restrict__ x,
                const float* __restrict__ W,
                const float* __restrict__ a_src,
                const float* __restrict__ a_dst,
                const unsigned* __restrict__ flag,
                float* __restrict__ h,
                float* __restrict__ as_out,
                float* __restrict__ ad_out)
{
    __shared__ float sW[CIN * 64];
    __shared__ float sx[4][CIN];
    const bool isbf = DYN ? (*flag != 0u) : false;
    const int tid = threadIdx.y * 64 + threadIdx.x;
    for (int i = tid; i < CIN * 64; i += 256) sW[i] = W[i];
    const int row0 = blockIdx.x * 4;
    for (int i = tid; i < 4 * CIN; i += 256) {
        int r = i / CIN, k = i - r * CIN;
        int row = row0 + r;
        float xv = 0.f;
        if (row < N_NODES) {
            long idx = (long)row * CIN + k;
            if (DYN && isbf) xv = bfbits(((const unsigned short*)x)[idx]);
            else             xv = ((const float*)x)[idx];
        }
        sx[r][k] = xv;
    }
    __syncthreads();

    const int col = threadIdx.x;
    const int row = row0 + threadIdx.y;
    float acc = 0.f;
#pragma unroll
    for (int k = 0; k < CIN; ++k)
        acc += sx[threadIdx.y][k] * sW[k * 64 + col];

    float vs = acc * a_src[col];
    float vd = acc * a_dst[col];
#pragma unroll
    for (int off = 32; off > 0; off >>= 1) {
        vs += __shfl_xor(vs, off, 64);
        vd += __shfl_xor(vd, off, 64);
    }
    if (row < N_NODES) {
        h[(long)row * 64 + col] = acc;
        if (col == 0) { as_out[row] = vs; ad_out[row] = vd; }
    }
}

// ---------------- Edge phase A: score + segment max ----------------
__global__ __launch_bounds__(256)
void edge_score(const int* __restrict__ ei,
                const float* __restrict__ as_, const float* __restrict__ ad_,
                float* __restrict__ escore, unsigned* __restrict__ mkey)
{
    int e = blockIdx.x * 256 + threadIdx.x;
    if (e >= ET_EDGES) return;
    int s, d;
    if (e < N_EDGES) { s = ei[e]; d = ei[N_EDGES + e]; }
    else             { s = d = e - N_EDGES; }
    float v = as_[s] + ad_[d];
    v = (v > 0.f) ? v : NEG_SLOPE * v;
    escore[e] = v;
    atomicMax(&mkey[d], fmap(v));
}

// ---------------- Edge phase B: exp + segment sum ----------------
__global__ __launch_bounds__(256)
void edge_exp(const int* __restrict__ ei,
              float* __restrict__ escore,
              const unsigned* __restrict__ mkey,
              float* __restrict__ denom)
{
    int e = blockIdx.x * 256 + threadIdx.x;
    if (e >= ET_EDGES) return;
    int d = (e < N_EDGES) ? ei[N_EDGES + e] : e - N_EDGES;
    float m = funmap(mkey[d]);
    float w = __expf(escore[e] - m);
    escore[e] = w;
    atomicAdd(&denom[d], w);
}

// ---------------- Edge phase C: weighted scatter ----------------
__global__ __launch_bounds__(256)
void edge_scatter(const int* __restrict__ ei,
                  const float* __restrict__ escore,
                  const float* __restrict__ denom,
                  const float* __restrict__ h,
                  float* __restrict__ acc)
{
    int e = blockIdx.x * 4 + (threadIdx.x >> 6);
    if (e >= ET_EDGES) return;
    int lane = threadIdx.x & 63;
    int s, d;
    if (e < N_EDGES) { s = ei[e]; d = ei[N_EDGES + e]; }
    else             { s = d = e - N_EDGES; }
    float alpha = escore[e] / denom[d];
    atomicAdd(&acc[(long)d * 64 + lane], alpha * h[(long)s * 64 + lane]);
}

// ---------------- Finalize: +bias, optional ELU, store ----------------
// OUT_DYN=false: always fp32 (internal layers). OUT_DYN=true: bf16 if flag.
template<bool DO_ELU, bool OUT_DYN>
__global__ __launch_bounds__(256)
void finalize(const float* __restrict__ acc,
              const float* __restrict__ b,
              void* __restrict__ out,
              const unsigned* __restrict__ flag)
{
    int idx = blockIdx.x * 256 + threadIdx.x;
    if (idx >= N_NODES * CH) return;
    float v = acc[idx] + b[idx & 63];
    if (DO_ELU) v = (v > 0.f) ? v : expm1f(v);
    if (OUT_DYN && *flag != 0u) ((bf16*)out)[idx] = __float2bfloat16(v);
    else                        ((float*)out)[idx] = v;
}

extern "C" void kernel_launch(void* const* d_in, const int* in_sizes, int n_in,
                              void* d_out, int out_size, void* d_ws, size_t ws_size,
                              hipStream_t stream)
{
    const void* x  = d_in[0];
    const int*  ei = (const int*)d_in[1];
    // raw param pointers (dtype unknown until detect runs)
    const void* pW1 = d_in[2],  *pas1 = d_in[3],  *pad1 = d_in[4],  *pb1 = d_in[5];
    const void* pW2 = d_in[6],  *pas2 = d_in[7],  *pad2 = d_in[8],  *pb2 = d_in[9];
    const void* pW3 = d_in[10], *pas3 = d_in[11], *pad3 = d_in[12], *pb3 = d_in[13];

    float* ws = (float*)d_ws;
    float*    bufA   = ws;                          // 3.2M  (h)
    float*    bufB   = bufA + (long)N_NODES * 64;   // 3.2M  (acc / layer io)
    float*    as_    = bufB + (long)N_NODES * 64;   // 50k
    float*    ad_    = as_ + N_NODES;
    float*    denom  = ad_ + N_NODES;
    unsigned* mkey   = (unsigned*)(denom + N_NODES);
    float*    escore = (float*)(mkey + N_NODES);    // 850k
    float*    prm    = escore + ET_EDGES;           // 16960 params fp32
    unsigned* flag   = (unsigned*)(prm + 20000);

    // packed fp32 param layout
    float* W1 = prm;          float* as1 = W1 + 8192; float* ad1 = as1 + 64; float* b1 = ad1 + 64;
    float* W2 = b1 + 64;      float* as2 = W2 + 4096; float* ad2 = as2 + 64; float* b2 = ad2 + 64;
    float* W3 = b2 + 64;      float* as3 = W3 + 4096; float* ad3 = as3 + 64; float* b3 = ad3 + 64;

    detect_dtype<<<1, 64, 0, stream>>>((const unsigned short*)pW1, flag);

    CvtArgs ca;
    const void* srcs[12] = {pW1, pas1, pad1, pb1, pW2, pas2, pad2, pb2, pW3, pas3, pad3, pb3};
    float*      dsts[12] = {W1, as1, ad1, b1, W2, as2, ad2, b2, W3, as3, ad3, b3};
    int         ns[12]   = {8192, 64, 64, 64, 4096, 64, 64, 64, 4096, 64, 64, 64};
    for (int i = 0; i < 12; ++i) { ca.src[i] = srcs[i]; ca.dst[i] = dsts[i]; ca.n[i] = ns[i]; }
    convert_params<<<dim3(8, 12), 256, 0, stream>>>(ca, flag);

    const int gemm_grid = (N_NODES + 3) / 4;
    const int edge_grid = (ET_EDGES + 255) / 256;
    const int scat_grid = (ET_EDGES + 3) / 4;
    const int node_grid = (N_NODES * CH + 255) / 256;
    const dim3 gemm_blk(64, 4);

    // ---------- Layer 1 (dual-dtype x, CIN=128) ----------
    gemm_alpha<128, true><<<gemm_grid, gemm_blk, 0, stream>>>(
        x, W1, as1, ad1, flag, bufA, as_, ad_);
    hipMemsetAsync(bufB, 0, (size_t)N_NODES * 64 * 4, stream);
    hipMemsetAsync(mkey, 0, (size_t)N_NODES * 4, stream);
    hipMemsetAsync(denom, 0, (size_t)N_NODES * 4, stream);
    edge_score<<<edge_grid, 256, 0, stream>>>(ei, as_, ad_, escore, mkey);
    edge_exp<<<edge_grid, 256, 0, stream>>>(ei, escore, mkey, denom);
    edge_scatter<<<scat_grid, 256, 0, stream>>>(ei, escore, denom, bufA, bufB);
    finalize<true, false><<<node_grid, 256, 0, stream>>>(bufB, b1, bufB, flag);

    // ---------- Layer 2 (fp32 internal, CIN=64) ----------
    gemm_alpha<64, false><<<gemm_grid, gemm_blk, 0, stream>>>(
        bufB, W2, as2, ad2, flag, bufA, as_, ad_);
    hipMemsetAsync(bufB, 0, (size_t)N_NODES * 64 * 4, stream);
    hipMemsetAsync(mkey, 0, (size_t)N_NODES * 4, stream);
    hipMemsetAsync(denom, 0, (size_t)N_NODES * 4, stream);
    edge_score<<<edge_grid, 256, 0, stream>>>(ei, as_, ad_, escore, mkey);
    edge_exp<<<edge_grid, 256, 0, stream>>>(ei, escore, mkey, denom);
    edge_scatter<<<scat_grid, 256, 0, stream>>>(ei, escore, denom, bufA, bufB);
    finalize<true, false><<<node_grid, 256, 0, stream>>>(bufB, b2, bufB, flag);

    // ---------- Layer 3 (fp32 internal, dual-dtype output, no ELU) ----------
    gemm_alpha<64, false><<<gemm_grid, gemm_blk, 0, stream>>>(
        bufB, W3, as3, ad3, flag, bufA, as_, ad_);
    hipMemsetAsync(bufB, 0, (size_t)N_NODES * 64 * 4, stream);
    hipMemsetAsync(mkey, 0, (size_t)N_NODES * 4, stream);
    hipMemsetAsync(denom, 0, (size_t)N_NODES * 4, stream);
    edge_score<<<edge_grid, 256, 0, stream>>>(ei, as_, ad_, escore, mkey);
    edge_exp<<<edge_grid, 256, 0, stream>>>(ei, escore, mkey, denom);
    edge_scatter<<<scat_grid, 256, 0, stream>>>(ei, escore, denom, bufA, bufB);
    finalize<false, true><<<node_grid, 256, 0, stream>>>(bufB, b3, d_out, flag);
}

// Round 3
// 493.360 us; speedup vs baseline: 2.1886x; 2.1886x over previous
//
#include <hip/hip_runtime.h>
#include <hip/hip_bf16.h>
#include <math.h>

#define N_NODES 50000
#define N_EDGES 800000
#define ET_EDGES (N_EDGES + N_NODES)   // with self-loops
#define CH 64
#define NEG_SLOPE 0.2f
#define NBLK ((N_NODES + 255) / 256)   // 196 scan blocks

typedef __hip_bfloat16 bf16;

__device__ inline float bfbits(unsigned short u) {
    return __uint_as_float(((unsigned)u) << 16);
}

// ---------------- dtype detection ----------------
// Reads W1's first 128 halves as bf16. True-bf16 weights are ~N(0,0.09) so
// every |v| <= 64. True-fp32 data makes the low halves random-exponent
// garbage: P(all 64 lanes pass) ~ 6e-19. flag=1 -> bf16, flag=0 -> fp32.
__global__ void detect_dtype(const unsigned short* __restrict__ w1raw,
                             unsigned* __restrict__ flag)
{
    int t = threadIdx.x;
    float v0 = bfbits(w1raw[2 * t]);
    float v1 = bfbits(w1raw[2 * t + 1]);
    bool bad = !(fabsf(v0) <= 64.f && fabsf(v1) <= 64.f);  // NaN -> bad
    unsigned long long b = __ballot(bad);
    if (t == 0) *flag = (b == 0ull) ? 1u : 0u;
}

// ---------------- param conversion (12 small tensors -> fp32) ----------------
struct CvtArgs {
    const void* src[12];
    float*      dst[12];
    int         n[12];
};

__global__ __launch_bounds__(256)
void convert_params(CvtArgs a, const unsigned* __restrict__ flag)
{
    bool isbf = (*flag != 0u);
    int which = blockIdx.y;
    int n = a.n[which];
    const void* s = a.src[which];
    float* d = a.dst[which];
    for (int i = blockIdx.x * 256 + threadIdx.x; i < n; i += gridDim.x * 256) {
        d[i] = isbf ? bfbits(((const unsigned short*)s)[i])
                    : ((const float*)s)[i];
    }
}

// ---------------- CSR build ----------------
__global__ __launch_bounds__(256)
void edge_hist(const int* __restrict__ ei, int* __restrict__ deg)
{
    int e = blockIdx.x * 256 + threadIdx.x;
    if (e >= ET_EDGES) return;
    int d = (e < N_EDGES) ? ei[N_EDGES + e] : e - N_EDGES;
    atomicAdd(&deg[d], 1);
}

__global__ __launch_bounds__(256)
void scan1(const int* __restrict__ deg, int* __restrict__ bsum)
{
    __shared__ int s[256];
    int i = blockIdx.x * 256 + threadIdx.x;
    s[threadIdx.x] = (i < N_NODES) ? deg[i] : 0;
    __syncthreads();
    for (int off = 128; off > 0; off >>= 1) {
        if (threadIdx.x < off) s[threadIdx.x] += s[threadIdx.x + off];
        __syncthreads();
    }
    if (threadIdx.x == 0) bsum[blockIdx.x] = s[0];
}

__global__ void scan2(int* __restrict__ bsum)
{
    if (threadIdx.x == 0) {
        int acc = 0;
        for (int i = 0; i < NBLK; ++i) { int t = bsum[i]; bsum[i] = acc; acc += t; }
    }
}

__global__ __launch_bounds__(256)
void scan3(const int* __restrict__ deg, const int* __restrict__ bsum,
           int* __restrict__ rowptr, int* __restrict__ cursor)
{
    __shared__ int s[256];
    int i = blockIdx.x * 256 + threadIdx.x;
    int v = (i < N_NODES) ? deg[i] : 0;
    s[threadIdx.x] = v;
    __syncthreads();
    for (int off = 1; off < 256; off <<= 1) {
        int t = (threadIdx.x >= off) ? s[threadIdx.x - off] : 0;
        __syncthreads();
        s[threadIdx.x] += t;
        __syncthreads();
    }
    if (i < N_NODES) {
        int excl = s[threadIdx.x] - v + bsum[blockIdx.x];
        rowptr[i] = excl;
        cursor[i] = excl;
    }
    if (i == 0) rowptr[N_NODES] = ET_EDGES;
}

__global__ __launch_bounds__(256)
void edge_fill(const int* __restrict__ ei, int* __restrict__ cursor,
               int* __restrict__ csr_src)
{
    int e = blockIdx.x * 256 + threadIdx.x;
    if (e >= ET_EDGES) return;
    int s, d;
    if (e < N_EDGES) { s = ei[e]; d = ei[N_EDGES + e]; }
    else             { s = d = e - N_EDGES; }
    int pos = atomicAdd(&cursor[d], 1);
    csr_src[pos] = s;
}

// ---------------- GEMM + alpha epilogue ----------------
// block = (64,4): tx = output column, ty = row-in-block; one wave per row.
template<int CIN, bool DYN>
__global__ __launch_bounds__(256)
void gemm_alpha(const void* __restrict__ x,
                const float* __restrict__ W,
                const float* __restrict__ a_src,
                const float* __restrict__ a_dst,
                const unsigned* __restrict__ flag,
                float* __restrict__ h,
                float* __restrict__ as_out,
                float* __restrict__ ad_out)
{
    __shared__ float sW[CIN * 64];
    __shared__ float sx[4][CIN];
    const bool isbf = DYN ? (*flag != 0u) : false;
    const int tid = threadIdx.y * 64 + threadIdx.x;
    for (int i = tid; i < CIN * 64; i += 256) sW[i] = W[i];
    const int row0 = blockIdx.x * 4;
    for (int i = tid; i < 4 * CIN; i += 256) {
        int r = i / CIN, k = i - r * CIN;
        int row = row0 + r;
        float xv = 0.f;
        if (row < N_NODES) {
            long idx = (long)row * CIN + k;
            if (DYN && isbf) xv = bfbits(((const unsigned short*)x)[idx]);
            else             xv = ((const float*)x)[idx];
        }
        sx[r][k] = xv;
    }
    __syncthreads();

    const int col = threadIdx.x;
    const int row = row0 + threadIdx.y;
    float acc = 0.f;
#pragma unroll
    for (int k = 0; k < CIN; ++k)
        acc += sx[threadIdx.y][k] * sW[k * 64 + col];

    float vs = acc * a_src[col];
    float vd = acc * a_dst[col];
#pragma unroll
    for (int off = 32; off > 0; off >>= 1) {
        vs += __shfl_xor(vs, off, 64);
        vd += __shfl_xor(vd, off, 64);
    }
    if (row < N_NODES) {
        h[(long)row * 64 + col] = acc;
        if (col == 0) { as_out[row] = vs; ad_out[row] = vd; }
    }
}

// ---------------- Fused GAT gather: softmax + weighted sum + bias(+ELU) ----
// One wave per destination node. Phase 1: lanes parallel over edges ->
// shuffle max & sum (no atomics). Phase 2: lanes = channels, sequential
// over edges, coalesced 256B h-row loads, register accumulate, one store.
template<bool DO_ELU, bool OUT_DYN>
__global__ __launch_bounds__(256)
void gat_gather(const int* __restrict__ rowptr,
                const int* __restrict__ csr_src,
                const float* __restrict__ as_,
                const float* __restrict__ ad_,
                const float* __restrict__ h,
                const float* __restrict__ bias,
                void* __restrict__ out,
                const unsigned* __restrict__ flag)
{
    int node = blockIdx.x * 4 + (threadIdx.x >> 6);
    if (node >= N_NODES) return;
    int lane = threadIdx.x & 63;
    int beg = rowptr[node];
    int deg = rowptr[node + 1] - beg;
    float adv = ad_[node];

    // phase 1: scores, max, exp-sum (first 64 edges cached in registers)
    int   my_src = 0;
    float my_e   = -1e30f;
    if (lane < deg) {
        my_src = csr_src[beg + lane];
        float v = as_[my_src] + adv;
        my_e = (v > 0.f) ? v : NEG_SLOPE * v;
    }
    float m = my_e;
    for (int j = 64 + lane; j < deg; j += 64) {
        int s2 = csr_src[beg + j];
        float v = as_[s2] + adv;
        v = (v > 0.f) ? v : NEG_SLOPE * v;
        m = fmaxf(m, v);
    }
#pragma unroll
    for (int off = 32; off > 0; off >>= 1) m = fmaxf(m, __shfl_xor(m, off, 64));

    float w = (lane < deg) ? __expf(my_e - m) : 0.f;
    float dsum = w;
    for (int j = 64 + lane; j < deg; j += 64) {
        int s2 = csr_src[beg + j];
        float v = as_[s2] + adv;
        v = (v > 0.f) ? v : NEG_SLOPE * v;
        dsum += __expf(v - m);
    }
#pragma unroll
    for (int off = 32; off > 0; off >>= 1) dsum += __shfl_xor(dsum, off, 64);
    float inv = 1.f / dsum;

    // phase 2: lanes = channels, iterate edges, coalesced h-row loads
    float acc = 0.f;
    int dmin = (deg < 64) ? deg : 64;
    for (int j = 0; j < dmin; ++j) {
        float wj = __shfl(w, j, 64);
        int   sj = __shfl(my_src, j, 64);
        acc += wj * h[(long)sj * 64 + lane];
    }
    for (int j = 64; j < deg; ++j) {          // rare (deg > 64)
        int sj = csr_src[beg + j];
        float v = as_[sj] + adv;
        v = (v > 0.f) ? v : NEG_SLOPE * v;
        acc += __expf(v - m) * h[(long)sj * 64 + lane];
    }
    acc = acc * inv + bias[lane];
    if (DO_ELU) acc = (acc > 0.f) ? acc : expm1f(acc);
    long oidx = (long)node * 64 + lane;
    if (OUT_DYN && *flag != 0u) ((bf16*)out)[oidx] = __float2bfloat16(acc);
    else                        ((float*)out)[oidx] = acc;
}

extern "C" void kernel_launch(void* const* d_in, const int* in_sizes, int n_in,
                              void* d_out, int out_size, void* d_ws, size_t ws_size,
                              hipStream_t stream)
{
    const void* x  = d_in[0];
    const int*  ei = (const int*)d_in[1];
    const void* pW1 = d_in[2],  *pas1 = d_in[3],  *pad1 = d_in[4],  *pb1 = d_in[5];
    const void* pW2 = d_in[6],  *pas2 = d_in[7],  *pad2 = d_in[8],  *pb2 = d_in[9];
    const void* pW3 = d_in[10], *pas3 = d_in[11], *pad3 = d_in[12], *pb3 = d_in[13];

    float* ws = (float*)d_ws;
    float*    bufA   = ws;                          // h (GEMM out)      12.8 MB
    float*    bufB   = bufA + (long)N_NODES * 64;   // layer io          12.8 MB
    float*    as_    = bufB + (long)N_NODES * 64;   // 200 KB
    float*    ad_    = as_ + N_NODES;
    int*      deg    = (int*)(ad_ + N_NODES);       // 200 KB
    int*      rowptr = deg + N_NODES;               // 200 KB (+1)
    int*      cursor = rowptr + N_NODES + 1;        // 200 KB
    int*      bsum   = cursor + N_NODES;            // 196
    int*      csr_src= bsum + NBLK;                 // 3.4 MB
    float*    prm    = (float*)(csr_src + ET_EDGES);
    unsigned* flag   = (unsigned*)(prm + 20000);

    float* W1 = prm;     float* as1 = W1 + 8192; float* ad1 = as1 + 64; float* b1 = ad1 + 64;
    float* W2 = b1 + 64; float* as2 = W2 + 4096; float* ad2 = as2 + 64; float* b2 = ad2 + 64;
    float* W3 = b2 + 64; float* as3 = W3 + 4096; float* ad3 = as3 + 64; float* b3 = ad3 + 64;

    detect_dtype<<<1, 64, 0, stream>>>((const unsigned short*)pW1, flag);

    CvtArgs ca;
    const void* srcs[12] = {pW1, pas1, pad1, pb1, pW2, pas2, pad2, pb2, pW3, pas3, pad3, pb3};
    float*      dsts[12] = {W1, as1, ad1, b1, W2, as2, ad2, b2, W3, as3, ad3, b3};
    int         ns[12]   = {8192, 64, 64, 64, 4096, 64, 64, 64, 4096, 64, 64, 64};
    for (int i = 0; i < 12; ++i) { ca.src[i] = srcs[i]; ca.dst[i] = dsts[i]; ca.n[i] = ns[i]; }
    convert_params<<<dim3(8, 12), 256, 0, stream>>>(ca, flag);

    // ---- CSR build (once per launch, shared by all 3 layers) ----
    const int edge_grid = (ET_EDGES + 255) / 256;
    hipMemsetAsync(deg, 0, (size_t)N_NODES * 4, stream);
    edge_hist<<<edge_grid, 256, 0, stream>>>(ei, deg);
    scan1<<<NBLK, 256, 0, stream>>>(deg, bsum);
    scan2<<<1, 64, 0, stream>>>(bsum);
    scan3<<<NBLK, 256, 0, stream>>>(deg, bsum, rowptr, cursor);
    edge_fill<<<edge_grid, 256, 0, stream>>>(ei, cursor, csr_src);

    const int gemm_grid = (N_NODES + 3) / 4;
    const int gat_grid  = (N_NODES + 3) / 4;
    const dim3 gemm_blk(64, 4);

    // ---------- Layer 1 ----------
    gemm_alpha<128, true><<<gemm_grid, gemm_blk, 0, stream>>>(
        x, W1, as1, ad1, flag, bufA, as_, ad_);
    gat_gather<true, false><<<gat_grid, 256, 0, stream>>>(
        rowptr, csr_src, as_, ad_, bufA, b1, bufB, flag);

    // ---------- Layer 2 ----------
    gemm_alpha<64, false><<<gemm_grid, gemm_blk, 0, stream>>>(
        bufB, W2, as2, ad2, flag, bufA, as_, ad_);
    gat_gather<true, false><<<gat_grid, 256, 0, stream>>>(
        rowptr, csr_src, as_, ad_, bufA, b2, bufB, flag);

    // ---------- Layer 3 ----------
    gemm_alpha<64, false><<<gemm_grid, gemm_blk, 0, stream>>>(
        bufB, W3, as3, ad3, flag, bufA, as_, ad_);
    gat_gather<false, true><<<gat_grid, 256, 0, stream>>>(
        rowptr, csr_src, as_, ad_, bufA, b3, d_out, flag);
}